// Round 1
// baseline (62.555 us; speedup 1.0000x reference)
//
#include <hip/hip_runtime.h>
#include <math.h>

#define NCLS 81
#define KMAX 200
#define CAP  2048   // per-batch detection list capacity (>= N=1500 worst case)
#define NMAXBOX 1500

// ---------------------------------------------------------------------------
// Kernel A: one 64-lane wave per (b, l) class. Compact candidates
// (prob > 0.7 => strict argmax => matches reference's labels_map!=0 masking),
// decode boxes for candidates only, exact greedy NMS, append selections to
// the per-batch list.
// ---------------------------------------------------------------------------
__global__ __launch_bounds__(64) void nms_per_class(
    const float* __restrict__ rois,     // [B,N,4]
    const float* __restrict__ deltas,   // [B,N,81*4]
    const float* __restrict__ probs,    // [B,N,81]
    float* __restrict__ entries,        // [B,CAP,8]
    int* __restrict__ counters,         // [B]
    int N) {
  const int bl = blockIdx.x;
  const int b  = bl / NCLS;
  const int l  = bl % NCLS;
  if (l == 0) return;  // background class can never exceed 0.7 after masking
  const int lane = threadIdx.x;

  __shared__ float s_score[NMAXBOX];
  __shared__ float s_box[NMAXBOX][4];
  __shared__ int   s_sel[KMAX];
  __shared__ float s_sel_score[KMAX];
  __shared__ int   s_base;

  // ---- candidate compaction (n-ascending order preserved) ----
  int m = 0;
  for (int n0 = 0; n0 < N; n0 += 64) {
    const int n = n0 + lane;
    float p = (n < N) ? probs[(size_t)(b * N + n) * NCLS + l] : 0.0f;
    const bool cand = p > 0.7f;
    const unsigned long long mask = __ballot(cand);
    if (cand) {
      const int idx = m + __popcll(mask & ((1ull << lane) - 1ull));
      const float* r = rois + (size_t)(b * N + n) * 4;
      const float ay1 = r[0], ax1 = r[1], ay2 = r[2], ax2 = r[3];
      const float h = ay2 - ay1, w = ax2 - ax1;
      const float cy = ay1 + 0.5f * h, cx = ax1 + 0.5f * w;
      const float* d = deltas + (size_t)(b * N + n) * (NCLS * 4) + l * 4;
      const float bh  = expf(d[2] * 0.2f) * h;
      const float bw  = expf(d[3] * 0.2f) * w;
      const float bcy = d[0] * 0.1f * h + cy;
      const float bcx = d[1] * 0.1f * w + cx;
      const float y1 = bcy - 0.5f * bh, x1 = bcx - 0.5f * bw;
      s_score[idx]  = p;
      s_box[idx][0] = y1;
      s_box[idx][1] = x1;
      s_box[idx][2] = y1 + bh;   // unclipped: NMS uses raw boxes
      s_box[idx][3] = x1 + bw;
    }
    m += __popcll(mask);
  }
  __syncthreads();

  // ---- greedy NMS (equivalent to reference's 200-step scan) ----
  int kept = 0;
  while (kept < KMAX) {
    // wave-parallel argmax, tie -> lowest candidate index (= lowest n)
    float best = -1.0f;
    int bi = -1;
    for (int i = lane; i < m; i += 64) {
      const float s = s_score[i];
      if (s > best) { best = s; bi = i; }   // strided ascending: first max kept
    }
    for (int off = 32; off > 0; off >>= 1) {
      const float ob = __shfl_down(best, off);
      const int   oi = __shfl_down(bi, off);
      if (ob > best || (ob == best && (unsigned)oi < (unsigned)bi)) {
        best = ob; bi = oi;
      }
    }
    best = __shfl(best, 0);
    bi   = __shfl(bi, 0);
    if (best <= 0.7f) break;   // all remaining picks would be invalid

    if (lane == 0) { s_sel[kept] = bi; s_sel_score[kept] = best; }

    const float by1 = s_box[bi][0], bx1 = s_box[bi][1];
    const float by2 = s_box[bi][2], bx2 = s_box[bi][3];
    const float a1 = (by2 - by1) * (bx2 - bx1);
    for (int i = lane; i < m; i += 64) {
      const float ty1 = s_box[i][0], tx1 = s_box[i][1];
      const float ty2 = s_box[i][2], tx2 = s_box[i][3];
      const float yy1 = fmaxf(by1, ty1), xx1 = fmaxf(bx1, tx1);
      const float yy2 = fminf(by2, ty2), xx2 = fminf(bx2, tx2);
      const float inter = fmaxf(yy2 - yy1, 0.0f) * fmaxf(xx2 - xx1, 0.0f);
      const float a2  = (ty2 - ty1) * (tx2 - tx1);
      const float uni = a1 + a2 - inter;
      const float iou = (uni > 0.0f) ? (inter / uni) : 0.0f;
      if (iou > 0.5f) s_score[i] = -INFINITY;   // self gets iou=1 -> suppressed
    }
    kept++;
    __syncthreads();
  }
  __syncthreads();

  // ---- append selections to per-batch list ----
  if (lane == 0) s_base = (kept > 0) ? atomicAdd(&counters[b], kept) : 0;
  __syncthreads();
  const int base = s_base;
  for (int i = lane; i < kept; i += 64) {
    const int slot = base + i;
    if (slot < CAP) {
      float* e = entries + (size_t)(b * CAP + slot) * 8;
      const int ci = s_sel[i];
      e[0] = s_sel_score[i];
      e[1] = (float)l;
      ((int*)e)[2] = l * KMAX + i;   // flat index for top_k tie-break
      e[3] = fminf(fmaxf(s_box[ci][0], 0.0f), 1.0f);
      e[4] = fminf(fmaxf(s_box[ci][1], 0.0f), 1.0f);
      e[5] = fminf(fmaxf(s_box[ci][2], 0.0f), 1.0f);
      e[6] = fminf(fmaxf(s_box[ci][3], 0.0f), 1.0f);
      e[7] = 0.0f;
    }
  }
}

// ---------------------------------------------------------------------------
// Kernel B: one block per batch. Bitonic sort CAP slots descending on
// key = (score_bits << 32) | ~flat_idx  (score desc, flat index asc),
// then emit top-200 (boxes, labels, scores), zero-filled beyond count.
// ---------------------------------------------------------------------------
__global__ __launch_bounds__(1024) void topk_per_batch(
    const float* __restrict__ entries,  // [B,CAP,8]
    const int* __restrict__ counters,   // [B]
    float* __restrict__ out) {
  const int b   = blockIdx.x;
  const int B   = gridDim.x;
  const int tid = threadIdx.x;

  __shared__ unsigned long long s_key[CAP];
  __shared__ int s_pay[CAP];

  int c = counters[b];
  if (c > CAP) c = CAP;

  for (int i = tid; i < CAP; i += 1024) {
    unsigned long long k = 0ull;
    if (i < c) {
      const float* e = entries + (size_t)(b * CAP + i) * 8;
      const unsigned sb = __float_as_uint(e[0]);           // score > 0.7 > 0
      const unsigned fi = (unsigned)(((const int*)e)[2]);
      k = ((unsigned long long)sb << 32) |
          (unsigned long long)(0xFFFFFFFFu - fi);
    }
    s_key[i] = k;
    s_pay[i] = i;
  }
  __syncthreads();

  for (int kk = 2; kk <= CAP; kk <<= 1) {
    for (int j = kk >> 1; j > 0; j >>= 1) {
      for (int i = tid; i < CAP; i += 1024) {
        const int ixj = i ^ j;
        if (ixj > i) {
          const bool up = ((i & kk) == 0);  // descending overall
          const unsigned long long a = s_key[i], bb = s_key[ixj];
          const bool sw = up ? (a < bb) : (a > bb);
          if (sw) {
            s_key[i] = bb; s_key[ixj] = a;
            const int t = s_pay[i]; s_pay[i] = s_pay[ixj]; s_pay[ixj] = t;
          }
        }
      }
      __syncthreads();
    }
  }

  if (tid < KMAX) {
    float sc = 0.0f, lb = 0.0f, b0 = 0.0f, b1 = 0.0f, b2 = 0.0f, b3 = 0.0f;
    if (tid < c) {
      const float* e = entries + (size_t)(b * CAP + s_pay[tid]) * 8;
      sc = e[0]; lb = e[1];
      b0 = e[3]; b1 = e[4]; b2 = e[5]; b3 = e[6];
    }
    float* ob = out + (size_t)b * (KMAX * 4) + (size_t)tid * 4;
    ob[0] = b0; ob[1] = b1; ob[2] = b2; ob[3] = b3;
    const size_t boxes_sz = (size_t)B * KMAX * 4;
    out[boxes_sz + (size_t)b * KMAX + tid] = lb;
    out[boxes_sz + (size_t)B * KMAX + (size_t)b * KMAX + tid] = sc;
  }
}

// ---------------------------------------------------------------------------
extern "C" void kernel_launch(void* const* d_in, const int* in_sizes, int n_in,
                              void* d_out, int out_size, void* d_ws, size_t ws_size,
                              hipStream_t stream) {
  const float* rois   = (const float*)d_in[0];
  const float* deltas = (const float*)d_in[1];
  const float* probs  = (const float*)d_in[2];
  float* out = (float*)d_out;

  const int B = 4;
  const int N = in_sizes[0] / (B * 4);   // 1500

  int* counters  = (int*)d_ws;
  float* entries = (float*)((char*)d_ws + 256);

  hipMemsetAsync(d_ws, 0, 256, stream);  // zero counters every launch
  hipLaunchKernelGGL(nms_per_class, dim3(B * NCLS), dim3(64), 0, stream,
                     rois, deltas, probs, entries, counters, N);
  hipLaunchKernelGGL(topk_per_batch, dim3(B), dim3(1024), 0, stream,
                     entries, counters, out);
}

// Round 2
// 45.474 us; speedup vs baseline: 1.3756x; 1.3756x over previous
//
#include <hip/hip_runtime.h>
#include <math.h>

#define NCLS 81
#define KMAX 200
#define NMAX 1536      // max rois supported in LDS (N=1500)
#define MAXIT 32       // max prefetch iters (N <= 2048)
#define SORT_CAP 2048  // >= max total detections per batch (<= N)

// ws layout: counts[B*NCLS] ints at offset 0; entries [B*NCLS][KMAX][8] floats at +4KB.

// ---------------------------------------------------------------------------
// Kernel A: one 64-lane wave per (b, l). prob > 0.7 => strict argmax => class
// l==0 can never pass; for l>=1 the labels_map!=0 mask is implied. Exact
// greedy NMS (equivalent to the reference's 200-step scan). No atomics: each
// block owns counts[b*NCLS+l] and entries[(b*NCLS+l)*KMAX ...].
// ---------------------------------------------------------------------------
__global__ __launch_bounds__(64) void nms_per_class(
    const float* __restrict__ rois,     // [B,N,4]
    const float* __restrict__ deltas,   // [B,N,81*4]
    const float* __restrict__ probs,    // [B,N,81]
    float* __restrict__ entries,        // [B*NCLS][KMAX][8]
    int* __restrict__ counts,           // [B*NCLS]
    int N) {
  const int bl = blockIdx.x;
  const int b  = bl / NCLS;
  const int l  = bl % NCLS;
  const int lane = threadIdx.x;
  if (l == 0) {                 // background: never passes threshold
    if (lane == 0) counts[bl] = 0;
    return;
  }

  __shared__ float s_score[NMAX];
  __shared__ float s_box[NMAX][4];
  __shared__ int   s_sel[KMAX];
  __shared__ float s_sel_score[KMAX];

  // ---- prefetch all strided prob loads (independent -> one latency round) --
  float pv[MAXIT];
  const int iters = (N + 63) >> 6;
  for (int it = 0; it < iters; ++it) {
    const int n = (it << 6) + lane;
    pv[it] = (n < N) ? probs[(size_t)(b * N + n) * NCLS + l] : 0.0f;
  }

  // ---- candidate compaction (n-ascending order preserved) ----
  int m = 0;
  for (int it = 0; it < iters; ++it) {
    const float p = pv[it];
    const bool cand = p > 0.7f;
    const unsigned long long mask = __ballot(cand);
    if (cand) {
      const int idx = m + __popcll(mask & ((1ull << lane) - 1ull));
      const int n = (it << 6) + lane;
      const float* r = rois + (size_t)(b * N + n) * 4;
      const float ay1 = r[0], ax1 = r[1], ay2 = r[2], ax2 = r[3];
      const float h = ay2 - ay1, w = ax2 - ax1;
      const float cy = ay1 + 0.5f * h, cx = ax1 + 0.5f * w;
      const float* d = deltas + (size_t)(b * N + n) * (NCLS * 4) + l * 4;
      const float bh  = expf(d[2] * 0.2f) * h;
      const float bw  = expf(d[3] * 0.2f) * w;
      const float bcy = d[0] * 0.1f * h + cy;
      const float bcx = d[1] * 0.1f * w + cx;
      const float y1 = bcy - 0.5f * bh, x1 = bcx - 0.5f * bw;
      s_score[idx]  = p;
      s_box[idx][0] = y1;
      s_box[idx][1] = x1;
      s_box[idx][2] = y1 + bh;   // unclipped: NMS uses raw boxes
      s_box[idx][3] = x1 + bw;
    }
    m += __popcll(mask);
  }
  __syncthreads();

  // ---- greedy NMS ----
  int kept = 0;
  while (kept < KMAX) {
    float best = -1.0f;
    int bi = -1;
    for (int i = lane; i < m; i += 64) {
      const float s = s_score[i];
      if (s > best) { best = s; bi = i; }   // strided ascending: first max kept
    }
    for (int off = 32; off > 0; off >>= 1) {
      const float ob = __shfl_down(best, off);
      const int   oi = __shfl_down(bi, off);
      if (ob > best || (ob == best && (unsigned)oi < (unsigned)bi)) {
        best = ob; bi = oi;
      }
    }
    best = __shfl(best, 0);
    bi   = __shfl(bi, 0);
    if (best <= 0.7f) break;   // all remaining picks invalid

    if (lane == 0) { s_sel[kept] = bi; s_sel_score[kept] = best; }

    const float by1 = s_box[bi][0], bx1 = s_box[bi][1];
    const float by2 = s_box[bi][2], bx2 = s_box[bi][3];
    const float a1 = (by2 - by1) * (bx2 - bx1);
    for (int i = lane; i < m; i += 64) {
      const float ty1 = s_box[i][0], tx1 = s_box[i][1];
      const float ty2 = s_box[i][2], tx2 = s_box[i][3];
      const float yy1 = fmaxf(by1, ty1), xx1 = fmaxf(bx1, tx1);
      const float yy2 = fminf(by2, ty2), xx2 = fminf(bx2, tx2);
      const float inter = fmaxf(yy2 - yy1, 0.0f) * fmaxf(xx2 - xx1, 0.0f);
      const float a2  = (ty2 - ty1) * (tx2 - tx1);
      const float uni = a1 + a2 - inter;
      const float iou = (uni > 0.0f) ? (inter / uni) : 0.0f;
      if (iou > 0.5f) s_score[i] = -INFINITY;   // self iou=1 -> suppressed
    }
    kept++;
    __syncthreads();
  }
  __syncthreads();

  // ---- write per-class results (no atomics) ----
  if (lane == 0) counts[bl] = kept;
  float* ebase = entries + (size_t)bl * KMAX * 8;
  for (int i = lane; i < kept; i += 64) {
    float* e = ebase + (size_t)i * 8;
    const int ci = s_sel[i];
    e[0] = s_sel_score[i];
    e[1] = fminf(fmaxf(s_box[ci][0], 0.0f), 1.0f);
    e[2] = fminf(fmaxf(s_box[ci][1], 0.0f), 1.0f);
    e[3] = fminf(fmaxf(s_box[ci][2], 0.0f), 1.0f);
    e[4] = fminf(fmaxf(s_box[ci][3], 0.0f), 1.0f);
  }
}

// ---------------------------------------------------------------------------
// Kernel B: one block per batch. Prefix-sum the 81 counts, gather 64-bit keys
// (score desc, flat index asc — low bits ARE the payload), bitonic sort only
// next_pow2(total) slots, emit top-200.
// ---------------------------------------------------------------------------
__global__ __launch_bounds__(1024) void topk_per_batch(
    const float* __restrict__ entries,  // [B*NCLS][KMAX][8]
    const int* __restrict__ counts,     // [B*NCLS]
    float* __restrict__ out, int B) {
  const int b   = blockIdx.x;
  const int tid = threadIdx.x;

  __shared__ int s_cnt[NCLS];
  __shared__ int s_off[NCLS];
  __shared__ int s_total, s_M;
  __shared__ unsigned long long s_key[SORT_CAP];

  if (tid < NCLS) s_cnt[tid] = counts[b * NCLS + tid];
  __syncthreads();
  if (tid == 0) {
    int acc = 0;
    for (int l = 0; l < NCLS; ++l) { s_off[l] = acc; acc += s_cnt[l]; }
    s_total = acc;
    int M = 64;
    while (M < acc) M <<= 1;
    s_M = M;
  }
  __syncthreads();
  const int c = s_total;
  const int M = s_M;     // c <= N <= SORT_CAP guaranteed

  for (int i = tid; i < M; i += 1024) s_key[i] = 0ull;
  __syncthreads();
  for (int j = tid; j < NCLS * KMAX; j += 1024) {
    const int l = j / KMAX, k = j - l * KMAX;
    if (k < s_cnt[l]) {
      const float sc = entries[((size_t)(b * NCLS + l) * KMAX + k) * 8];
      const unsigned sb = __float_as_uint(sc);           // score > 0.7 > 0
      s_key[s_off[l] + k] =
          ((unsigned long long)sb << 32) |
          (unsigned long long)(0xFFFFFFFFu - (unsigned)(l * KMAX + k));
    }
  }
  __syncthreads();

  for (int kk = 2; kk <= M; kk <<= 1) {
    for (int j2 = kk >> 1; j2 > 0; j2 >>= 1) {
      for (int i = tid; i < M; i += 1024) {
        const int ixj = i ^ j2;
        if (ixj > i) {
          const bool up = ((i & kk) == 0);  // descending overall
          const unsigned long long a = s_key[i], bb = s_key[ixj];
          const bool sw = up ? (a < bb) : (a > bb);
          if (sw) { s_key[i] = bb; s_key[ixj] = a; }
        }
      }
      __syncthreads();
    }
  }

  if (tid < KMAX) {
    float sc = 0.0f, lb = 0.0f, b0 = 0.0f, b1 = 0.0f, b2 = 0.0f, b3 = 0.0f;
    if (tid < c) {
      const unsigned long long k = s_key[tid];
      const unsigned fi = 0xFFFFFFFFu - (unsigned)(k & 0xFFFFFFFFull);
      const int l = fi / KMAX, kk2 = fi - l * KMAX;
      const float* e = entries + ((size_t)(b * NCLS + l) * KMAX + kk2) * 8;
      sc = e[0];
      lb = (float)l;
      b0 = e[1]; b1 = e[2]; b2 = e[3]; b3 = e[4];
    }
    float* ob = out + (size_t)b * (KMAX * 4) + (size_t)tid * 4;
    ob[0] = b0; ob[1] = b1; ob[2] = b2; ob[3] = b3;
    const size_t boxes_sz = (size_t)B * KMAX * 4;
    out[boxes_sz + (size_t)b * KMAX + tid] = lb;
    out[boxes_sz + (size_t)B * KMAX + (size_t)b * KMAX + tid] = sc;
  }
}

// ---------------------------------------------------------------------------
extern "C" void kernel_launch(void* const* d_in, const int* in_sizes, int n_in,
                              void* d_out, int out_size, void* d_ws, size_t ws_size,
                              hipStream_t stream) {
  const float* rois   = (const float*)d_in[0];
  const float* deltas = (const float*)d_in[1];
  const float* probs  = (const float*)d_in[2];
  float* out = (float*)d_out;

  const int B = 4;
  const int N = in_sizes[0] / (B * 4);   // 1500

  int* counts    = (int*)d_ws;
  float* entries = (float*)((char*)d_ws + 4096);

  hipLaunchKernelGGL(nms_per_class, dim3(B * NCLS), dim3(64), 0, stream,
                     rois, deltas, probs, entries, counts, N);
  hipLaunchKernelGGL(topk_per_batch, dim3(B), dim3(1024), 0, stream,
                     entries, counts, out, B);
}

// Round 3
// 42.815 us; speedup vs baseline: 1.4611x; 1.0621x over previous
//
#include <hip/hip_runtime.h>
#include <math.h>

#define NCLS 81
#define KMAX 200
#define NMAX 1536      // max candidates stageable in LDS (>= N=1500)
#define SORT_CAP 2048  // >= max total detections per batch (<= N)

// ws layout: counts[B*NCLS] ints at offset 0; entries [B*NCLS][KMAX][8] floats at +4KB.

// ---------------------------------------------------------------------------
// Shared device body: candidate compaction + exact greedy NMS + per-class
// output. prob > 0.7 => strict argmax (softmax row sums to 1) => class 0 can
// never pass and labels_map!=0 is implied for l>=1.
// ---------------------------------------------------------------------------
template <int NT>
__global__ __launch_bounds__(64) void nms_per_class(
    const float* __restrict__ rois,     // [B,NT,4]
    const float* __restrict__ deltas,   // [B,NT,81*4]
    const float* __restrict__ probs,    // [B,NT,81]
    float* __restrict__ entries,        // [B*NCLS][KMAX][8]
    int* __restrict__ counts) {         // [B*NCLS]
  constexpr int ITERS = (NT + 63) / 64;
  const int bl = blockIdx.x;
  const int b  = bl / NCLS;
  const int l  = bl % NCLS;
  const int lane = threadIdx.x;
  if (l == 0) {                 // background: never passes threshold
    if (lane == 0) counts[bl] = 0;
    return;
  }

  __shared__ float s_score[NMAX];
  __shared__ float s_box[NMAX][4];
  __shared__ int   s_sel[KMAX];
  __shared__ float s_sel_score[KMAX];

  // ---- prefetch all strided prob loads; compile-time bound => registers ----
  float pv[ITERS];
#pragma unroll
  for (int it = 0; it < ITERS; ++it) {
    const int n = (it << 6) + lane;
    pv[it] = (n < NT) ? probs[(size_t)(b * NT + n) * NCLS + l] : 0.0f;
  }

  // ---- candidate compaction (n-ascending order preserved) ----
  int m = 0;
#pragma unroll
  for (int it = 0; it < ITERS; ++it) {
    const float p = pv[it];
    const bool cand = p > 0.7f;
    const unsigned long long mask = __ballot(cand);
    if (cand) {
      const int idx = m + __popcll(mask & ((1ull << lane) - 1ull));
      const int n = (it << 6) + lane;
      const float* r = rois + (size_t)(b * NT + n) * 4;
      const float ay1 = r[0], ax1 = r[1], ay2 = r[2], ax2 = r[3];
      const float h = ay2 - ay1, w = ax2 - ax1;
      const float cy = ay1 + 0.5f * h, cx = ax1 + 0.5f * w;
      const float* d = deltas + (size_t)(b * NT + n) * (NCLS * 4) + l * 4;
      const float bh  = expf(d[2] * 0.2f) * h;
      const float bw  = expf(d[3] * 0.2f) * w;
      const float bcy = d[0] * 0.1f * h + cy;
      const float bcx = d[1] * 0.1f * w + cx;
      const float y1 = bcy - 0.5f * bh, x1 = bcx - 0.5f * bw;
      s_score[idx]  = p;
      s_box[idx][0] = y1;
      s_box[idx][1] = x1;
      s_box[idx][2] = y1 + bh;   // unclipped: NMS uses raw boxes
      s_box[idx][3] = x1 + bw;
    }
    m += __popcll(mask);
  }
  __syncthreads();

  // ---- greedy NMS (equivalent to the reference's 200-step scan) ----
  int kept = 0;
  while (kept < KMAX) {
    float best = -1.0f;
    int bi = -1;
    for (int i = lane; i < m; i += 64) {
      const float s = s_score[i];
      if (s > best) { best = s; bi = i; }   // strided ascending: first max kept
    }
    for (int off = 32; off > 0; off >>= 1) {
      const float ob = __shfl_down(best, off);
      const int   oi = __shfl_down(bi, off);
      if (ob > best || (ob == best && (unsigned)oi < (unsigned)bi)) {
        best = ob; bi = oi;
      }
    }
    best = __shfl(best, 0);
    bi   = __shfl(bi, 0);
    if (best <= 0.7f) break;   // all remaining picks invalid

    if (lane == 0) { s_sel[kept] = bi; s_sel_score[kept] = best; }

    const float by1 = s_box[bi][0], bx1 = s_box[bi][1];
    const float by2 = s_box[bi][2], bx2 = s_box[bi][3];
    const float a1 = (by2 - by1) * (bx2 - bx1);
    for (int i = lane; i < m; i += 64) {
      const float ty1 = s_box[i][0], tx1 = s_box[i][1];
      const float ty2 = s_box[i][2], tx2 = s_box[i][3];
      const float yy1 = fmaxf(by1, ty1), xx1 = fmaxf(bx1, tx1);
      const float yy2 = fminf(by2, ty2), xx2 = fminf(bx2, tx2);
      const float inter = fmaxf(yy2 - yy1, 0.0f) * fmaxf(xx2 - xx1, 0.0f);
      const float a2  = (ty2 - ty1) * (tx2 - tx1);
      const float uni = a1 + a2 - inter;
      const float iou = (uni > 0.0f) ? (inter / uni) : 0.0f;
      if (iou > 0.5f) s_score[i] = -INFINITY;   // self iou=1 -> suppressed
    }
    kept++;
    __syncthreads();
  }
  __syncthreads();

  // ---- write per-class results (no atomics) ----
  if (lane == 0) counts[bl] = kept;
  float* ebase = entries + (size_t)bl * KMAX * 8;
  for (int i = lane; i < kept; i += 64) {
    float* e = ebase + (size_t)i * 8;
    const int ci = s_sel[i];
    e[0] = s_sel_score[i];
    e[1] = fminf(fmaxf(s_box[ci][0], 0.0f), 1.0f);
    e[2] = fminf(fmaxf(s_box[ci][1], 0.0f), 1.0f);
    e[3] = fminf(fmaxf(s_box[ci][2], 0.0f), 1.0f);
    e[4] = fminf(fmaxf(s_box[ci][3], 0.0f), 1.0f);
  }
}

// Runtime-N fallback: no prefetch array (avoids scratch), load inside loop.
__global__ __launch_bounds__(64) void nms_per_class_rt(
    const float* __restrict__ rois, const float* __restrict__ deltas,
    const float* __restrict__ probs, float* __restrict__ entries,
    int* __restrict__ counts, int N) {
  const int bl = blockIdx.x;
  const int b  = bl / NCLS;
  const int l  = bl % NCLS;
  const int lane = threadIdx.x;
  if (l == 0) { if (lane == 0) counts[bl] = 0; return; }

  __shared__ float s_score[NMAX];
  __shared__ float s_box[NMAX][4];
  __shared__ int   s_sel[KMAX];
  __shared__ float s_sel_score[KMAX];

  int m = 0;
  for (int n0 = 0; n0 < N; n0 += 64) {
    const int n = n0 + lane;
    const float p = (n < N) ? probs[(size_t)(b * N + n) * NCLS + l] : 0.0f;
    const bool cand = p > 0.7f;
    const unsigned long long mask = __ballot(cand);
    if (cand) {
      const int idx = m + __popcll(mask & ((1ull << lane) - 1ull));
      const float* r = rois + (size_t)(b * N + n) * 4;
      const float ay1 = r[0], ax1 = r[1], ay2 = r[2], ax2 = r[3];
      const float h = ay2 - ay1, w = ax2 - ax1;
      const float cy = ay1 + 0.5f * h, cx = ax1 + 0.5f * w;
      const float* d = deltas + (size_t)(b * N + n) * (NCLS * 4) + l * 4;
      const float bh  = expf(d[2] * 0.2f) * h;
      const float bw  = expf(d[3] * 0.2f) * w;
      const float bcy = d[0] * 0.1f * h + cy;
      const float bcx = d[1] * 0.1f * w + cx;
      const float y1 = bcy - 0.5f * bh, x1 = bcx - 0.5f * bw;
      s_score[idx]  = p;
      s_box[idx][0] = y1; s_box[idx][1] = x1;
      s_box[idx][2] = y1 + bh; s_box[idx][3] = x1 + bw;
    }
    m += __popcll(mask);
  }
  __syncthreads();

  int kept = 0;
  while (kept < KMAX) {
    float best = -1.0f; int bi = -1;
    for (int i = lane; i < m; i += 64) {
      const float s = s_score[i];
      if (s > best) { best = s; bi = i; }
    }
    for (int off = 32; off > 0; off >>= 1) {
      const float ob = __shfl_down(best, off);
      const int   oi = __shfl_down(bi, off);
      if (ob > best || (ob == best && (unsigned)oi < (unsigned)bi)) { best = ob; bi = oi; }
    }
    best = __shfl(best, 0); bi = __shfl(bi, 0);
    if (best <= 0.7f) break;
    if (lane == 0) { s_sel[kept] = bi; s_sel_score[kept] = best; }
    const float by1 = s_box[bi][0], bx1 = s_box[bi][1];
    const float by2 = s_box[bi][2], bx2 = s_box[bi][3];
    const float a1 = (by2 - by1) * (bx2 - bx1);
    for (int i = lane; i < m; i += 64) {
      const float ty1 = s_box[i][0], tx1 = s_box[i][1];
      const float ty2 = s_box[i][2], tx2 = s_box[i][3];
      const float yy1 = fmaxf(by1, ty1), xx1 = fmaxf(bx1, tx1);
      const float yy2 = fminf(by2, ty2), xx2 = fminf(bx2, tx2);
      const float inter = fmaxf(yy2 - yy1, 0.0f) * fmaxf(xx2 - xx1, 0.0f);
      const float a2  = (ty2 - ty1) * (tx2 - tx1);
      const float uni = a1 + a2 - inter;
      const float iou = (uni > 0.0f) ? (inter / uni) : 0.0f;
      if (iou > 0.5f) s_score[i] = -INFINITY;
    }
    kept++;
    __syncthreads();
  }
  __syncthreads();

  if (lane == 0) counts[bl] = kept;
  float* ebase = entries + (size_t)bl * KMAX * 8;
  for (int i = lane; i < kept; i += 64) {
    float* e = ebase + (size_t)i * 8;
    const int ci = s_sel[i];
    e[0] = s_sel_score[i];
    e[1] = fminf(fmaxf(s_box[ci][0], 0.0f), 1.0f);
    e[2] = fminf(fmaxf(s_box[ci][1], 0.0f), 1.0f);
    e[3] = fminf(fmaxf(s_box[ci][2], 0.0f), 1.0f);
    e[4] = fminf(fmaxf(s_box[ci][3], 0.0f), 1.0f);
  }
}

// ---------------------------------------------------------------------------
// Kernel B: one block per batch. Prefix-sum the 81 counts, gather 64-bit keys
// (score desc, flat index asc — low bits ARE the payload), bitonic sort only
// next_pow2(total) slots, emit top-200.
// ---------------------------------------------------------------------------
__global__ __launch_bounds__(1024) void topk_per_batch(
    const float* __restrict__ entries,  // [B*NCLS][KMAX][8]
    const int* __restrict__ counts,     // [B*NCLS]
    float* __restrict__ out, int B) {
  const int b   = blockIdx.x;
  const int tid = threadIdx.x;

  __shared__ int s_cnt[NCLS];
  __shared__ int s_off[NCLS];
  __shared__ int s_total, s_M;
  __shared__ unsigned long long s_key[SORT_CAP];

  if (tid < NCLS) s_cnt[tid] = counts[b * NCLS + tid];
  __syncthreads();
  if (tid == 0) {
    int acc = 0;
    for (int l = 0; l < NCLS; ++l) { s_off[l] = acc; acc += s_cnt[l]; }
    s_total = acc;
    int M = 64;
    while (M < acc) M <<= 1;
    s_M = M;
  }
  __syncthreads();
  const int c = s_total;
  const int M = s_M;     // c <= N <= SORT_CAP guaranteed

  for (int i = tid; i < M; i += 1024) s_key[i] = 0ull;
  __syncthreads();
  for (int j = tid; j < NCLS * KMAX; j += 1024) {
    const int l = j / KMAX, k = j - l * KMAX;
    if (k < s_cnt[l]) {
      const float sc = entries[((size_t)(b * NCLS + l) * KMAX + k) * 8];
      const unsigned sb = __float_as_uint(sc);           // score > 0.7 > 0
      s_key[s_off[l] + k] =
          ((unsigned long long)sb << 32) |
          (unsigned long long)(0xFFFFFFFFu - (unsigned)(l * KMAX + k));
    }
  }
  __syncthreads();

  for (int kk = 2; kk <= M; kk <<= 1) {
    for (int j2 = kk >> 1; j2 > 0; j2 >>= 1) {
      for (int i = tid; i < M; i += 1024) {
        const int ixj = i ^ j2;
        if (ixj > i) {
          const bool up = ((i & kk) == 0);  // descending overall
          const unsigned long long a = s_key[i], bb = s_key[ixj];
          const bool sw = up ? (a < bb) : (a > bb);
          if (sw) { s_key[i] = bb; s_key[ixj] = a; }
        }
      }
      __syncthreads();
    }
  }

  if (tid < KMAX) {
    float sc = 0.0f, lb = 0.0f, b0 = 0.0f, b1 = 0.0f, b2 = 0.0f, b3 = 0.0f;
    if (tid < c) {
      const unsigned long long k = s_key[tid];
      const unsigned fi = 0xFFFFFFFFu - (unsigned)(k & 0xFFFFFFFFull);
      const int l = fi / KMAX, kk2 = fi - l * KMAX;
      const float* e = entries + ((size_t)(b * NCLS + l) * KMAX + kk2) * 8;
      sc = e[0];
      lb = (float)l;
      b0 = e[1]; b1 = e[2]; b2 = e[3]; b3 = e[4];
    }
    float* ob = out + (size_t)b * (KMAX * 4) + (size_t)tid * 4;
    ob[0] = b0; ob[1] = b1; ob[2] = b2; ob[3] = b3;
    const size_t boxes_sz = (size_t)B * KMAX * 4;
    out[boxes_sz + (size_t)b * KMAX + tid] = lb;
    out[boxes_sz + (size_t)B * KMAX + (size_t)b * KMAX + tid] = sc;
  }
}

// ---------------------------------------------------------------------------
extern "C" void kernel_launch(void* const* d_in, const int* in_sizes, int n_in,
                              void* d_out, int out_size, void* d_ws, size_t ws_size,
                              hipStream_t stream) {
  const float* rois   = (const float*)d_in[0];
  const float* deltas = (const float*)d_in[1];
  const float* probs  = (const float*)d_in[2];
  float* out = (float*)d_out;

  const int B = 4;
  const int N = in_sizes[0] / (B * 4);   // 1500

  int* counts    = (int*)d_ws;
  float* entries = (float*)((char*)d_ws + 4096);

  if (N == 1500) {
    hipLaunchKernelGGL((nms_per_class<1500>), dim3(B * NCLS), dim3(64), 0,
                       stream, rois, deltas, probs, entries, counts);
  } else {
    hipLaunchKernelGGL(nms_per_class_rt, dim3(B * NCLS), dim3(64), 0, stream,
                       rois, deltas, probs, entries, counts, N);
  }
  hipLaunchKernelGGL(topk_per_batch, dim3(B), dim3(1024), 0, stream,
                     entries, counts, out, B);
}